// Round 3
// baseline (2439.087 us; speedup 1.0000x reference)
//
#include <hip/hip_runtime.h>
#include <hip/hip_bf16.h>

// FNO2D: B=8, C=64, H=W=256, MODES=20.
// Spectral conv as partial DFTs (only 40x20 modes used). In-place activations.
// BN+ReLU fused into next-layer dftw (l=1..3) and into fc12 (layer 3) -> no bn_k.

// ---------------------------------------------------------------- init tables
__global__ __launch_bounds__(256) void init_k(const float* __restrict__ cw,
                                              float* __restrict__ costab, float* __restrict__ sintab,
                                              float* __restrict__ EA, float* __restrict__ Tw,
                                              float* __restrict__ cwT, float* __restrict__ stats) {
    int idx = blockIdx.x * 256 + threadIdx.x;
    const float PH = 6.28318530717958647692f / 256.f;
    if (idx < 256) {
        float s, c; sincosf(idx * PH, &s, &c);
        costab[idx] = c; sintab[idx] = s;
    } else if (idx < 256 + 10240) {            // EA[w][2*ky+p]: forward DFT along W
        int e = idx - 256;
        int w = e / 40, n = e % 40, ky = n >> 1;
        int r = (ky * w) & 255;
        float s, c; sincosf(r * PH, &s, &c);
        EA[e] = (n & 1) ? -s : c;
    } else if (idx < 256 + 20480) {            // Tw[kp][w]: irfft along W (ortho, Im(z0) dropped)
        int e = idx - 10496;
        int kp = e >> 8, w = e & 255;
        int ky = kp >> 1, p = kp & 1;
        int r = (ky * w) & 255;
        float s, c; sincosf(r * PH, &s, &c);
        float v;
        if (ky == 0) v = p ? 0.f : (1.f / 16.f);
        else         v = p ? (-2.f / 16.f) * s : (2.f / 16.f) * c;
        Tw[e] = v;
    } else if (idx < 256 + 20480 + 16384) {    // cwT[l][i][o] = cw[l][o][i]
        int e = idx - 20736;
        int l = e >> 12, r2 = e & 4095;
        int i = r2 >> 6, o = r2 & 63;
        cwT[e] = cw[(l << 12) + (o << 6) + i];
    } else if (idx < 256 + 20480 + 16384 + 512) {
        stats[idx - 37120] = 0.f;              // zero BN-stats accumulators
    }
}

// ------------------------------------------------------------------------ fc0
__global__ __launch_bounds__(256) void fc0_k(const float* __restrict__ x,
                                             const float* __restrict__ w,
                                             const float* __restrict__ bias,
                                             float* __restrict__ outb) {
    __shared__ float ws[768];
    __shared__ float bs[64];
    int tid = threadIdx.x;
    for (int i = tid; i < 768; i += 256) ws[i] = w[i];
    if (tid < 64) bs[tid] = bias[tid];
    __syncthreads();
    int pix = blockIdx.x * 256 + tid;           // 0..524287
    int b = pix >> 16, hw = pix & 65535;
    float xv[12];
#pragma unroll
    for (int t = 0; t < 12; ++t) xv[t] = x[pix * 12 + t];
    int base = (b << 22) + hw;
    for (int c = 0; c < 64; ++c) {
        float a = bs[c];
#pragma unroll
        for (int t = 0; t < 12; ++t) a += xv[t] * ws[t * 64 + c];
        outb[base + (c << 16)] = a;
    }
}

// ------------------- stage A: DFT along W (GEMM), optionally fused BN+ReLU
// If fuse: X holds pre-activations of the PREVIOUS layer; normalize with (sc,sh)
// of this block's constant channel, ReLU, write back in-place, then DFT.
// T[row][2ky+p] = sum_w Xn[row][w] * EA[w][2ky+p],  rows = (b*64+c)*256+h
__global__ __launch_bounds__(128) void dftw_k(float* __restrict__ X,
                                              const float* __restrict__ EA,
                                              float* __restrict__ T,
                                              const float* __restrict__ statsl,
                                              const float* __restrict__ g,
                                              const float* __restrict__ bt,
                                              int fuse) {
    __shared__ __align__(16) float Xs[32 * 68];   // transposed [k][m]
    __shared__ float Es[32 * 40];
    int tid = threadIdx.x;
    int tm = tid >> 3, tn = tid & 7;
    int row0 = blockIdx.x << 6;
    float sc = 1.f, sh = 0.f;
    if (fuse) {
        int c = (row0 >> 8) & 63;
        float mean = statsl[c] * (1.f / 524288.f);
        float var = statsl[64 + c] * (1.f / 524288.f) - mean * mean;
        sc = g[c] * rsqrtf(var + 1e-5f);
        sh = bt[c] - mean * sc;
    }
    float acc[4][5];
#pragma unroll
    for (int i = 0; i < 4; ++i)
#pragma unroll
        for (int j = 0; j < 5; ++j) acc[i][j] = 0.f;

    for (int kc = 0; kc < 256; kc += 32) {
        __syncthreads();
#pragma unroll
        for (int r = 0; r < 4; ++r) {
            int m = tm + (r << 4);
            float4 v = *(const float4*)&X[(row0 + m) * 256 + kc + (tn << 2)];
            if (fuse) {
                v.x = fmaxf(fmaf(v.x, sc, sh), 0.f);
                v.y = fmaxf(fmaf(v.y, sc, sh), 0.f);
                v.z = fmaxf(fmaf(v.z, sc, sh), 0.f);
                v.w = fmaxf(fmaf(v.w, sc, sh), 0.f);
                *(float4*)&X[(row0 + m) * 256 + kc + (tn << 2)] = v;
            }
            int kb = tn << 2;
            Xs[(kb + 0) * 68 + m] = v.x;
            Xs[(kb + 1) * 68 + m] = v.y;
            Xs[(kb + 2) * 68 + m] = v.z;
            Xs[(kb + 3) * 68 + m] = v.w;
        }
        for (int i = tid; i < 1280; i += 128) Es[i] = EA[kc * 40 + i];
        __syncthreads();
#pragma unroll 8
        for (int kk = 0; kk < 32; ++kk) {
            float4 a = *(const float4*)&Xs[kk * 68 + (tm << 2)];
#pragma unroll
            for (int j = 0; j < 5; ++j) {
                float bv = Es[kk * 40 + tn * 5 + j];
                acc[0][j] += a.x * bv;
                acc[1][j] += a.y * bv;
                acc[2][j] += a.z * bv;
                acc[3][j] += a.w * bv;
            }
        }
    }
#pragma unroll
    for (int i = 0; i < 4; ++i) {
        int row = row0 + (tm << 2) + i;
#pragma unroll
        for (int j = 0; j < 5; ++j) T[row * 40 + tn * 5 + j] = acc[i][j];
    }
}

// ------------------------------------------- stage B: DFT along H (256 -> 40 rows)
// XF[b][kx][ky][2c+p], scale 1/256 (full forward ortho)
__global__ __launch_bounds__(256) void dfth_k(const float* __restrict__ T,
                                              const float* __restrict__ ct, const float* __restrict__ st,
                                              float* __restrict__ XF) {
    __shared__ __align__(16) float Ts[10240];
    __shared__ float cts[256], sts[256];
    int tid = threadIdx.x;
    int bc = blockIdx.x;
    for (int i = tid; i < 10240; i += 256) Ts[i] = T[bc * 10240 + i];
    cts[tid] = ct[tid]; sts[tid] = st[tid];
    __syncthreads();
    if (tid < 200) {
        int kxi = tid / 5, kyg = tid % 5;
        int kxa = kxi < 20 ? kxi : kxi + 216;
        float ar0 = 0, ai0 = 0, ar1 = 0, ai1 = 0, ar2 = 0, ai2 = 0, ar3 = 0, ai3 = 0;
        int r = 0;
        for (int h = 0; h < 256; ++h) {
            float cc = cts[r], sv = sts[r];
            r = (r + kxa) & 255;
            float4 v0 = *(const float4*)&Ts[h * 40 + (kyg << 3)];
            float4 v1 = *(const float4*)&Ts[h * 40 + (kyg << 3) + 4];
            ar0 += v0.x * cc + v0.y * sv;  ai0 += v0.y * cc - v0.x * sv;
            ar1 += v0.z * cc + v0.w * sv;  ai1 += v0.w * cc - v0.z * sv;
            ar2 += v1.x * cc + v1.y * sv;  ai2 += v1.y * cc - v1.x * sv;
            ar3 += v1.z * cc + v1.w * sv;  ai3 += v1.w * cc - v1.z * sv;
        }
        int b = bc >> 6, c = bc & 63;
        const float s = 1.f / 256.f;
        int A = (b * 40 + kxi) * 20 + (kyg << 2);
        float2* O = (float2*)XF;
        O[(A + 0) * 64 + c] = make_float2(ar0 * s, ai0 * s);
        O[(A + 1) * 64 + c] = make_float2(ar1 * s, ai1 * s);
        O[(A + 2) * 64 + c] = make_float2(ar2 * s, ai2 * s);
        O[(A + 3) * 64 + c] = make_float2(ar3 * s, ai3 * s);
    }
}

// ---------------------------------------------------------------- mode einsum
// YF[b][x][y][o] = sum_i XF[b][x][y][i] * w[i][o][x'][y]   (w1 for x<20, w2 else)
__global__ __launch_bounds__(512) void eins_k(const float* __restrict__ XF,
                                              const float* __restrict__ w1, const float* __restrict__ w2,
                                              float* __restrict__ YF) {
    __shared__ float xfs[1024];
    int tid = threadIdx.x;
    int x = blockIdx.x / 20, y = blockIdx.x % 20;
    for (int i = tid; i < 1024; i += 512) {
        int b = i >> 7, rr = i & 127;
        xfs[i] = XF[(b * 40 + x) * 2560 + y * 128 + rr];
    }
    __syncthreads();
    int b = tid >> 6, o = tid & 63;
    const float* wp = (x < 20) ? (w1 + (x * 20 + y) * 2) : (w2 + ((x - 20) * 20 + y) * 2);
    float ar = 0.f, ai = 0.f;
#pragma unroll 8
    for (int i = 0; i < 64; ++i) {
        float2 wv = *(const float2*)&wp[(i * 64 + o) * 800];
        float xr = xfs[(b << 7) + (i << 1)];
        float xi = xfs[(b << 7) + (i << 1) + 1];
        ar += xr * wv.x - xi * wv.y;
        ai += xr * wv.y + xi * wv.x;
    }
    ((float2*)YF)[((b * 40 + x) * 20 + y) * 64 + o] = make_float2(ar, ai);
}

// ------------------------------------ stage C: inverse (full complex) DFT along H
// Z[b][co][h][kp], scale 1/16
__global__ __launch_bounds__(256) void idfth_k(const float* __restrict__ YF,
                                               const float* __restrict__ ct, const float* __restrict__ st,
                                               float* __restrict__ Z) {
    __shared__ __align__(16) float yfs[1600];
    __shared__ float cts[256], sts[256];
    int tid = threadIdx.x;
    int bc = blockIdx.x;
    int b = bc >> 6, co = bc & 63;
    for (int i = tid; i < 800; i += 256) {
        int kx = i / 20, ky = i % 20;
        float2 v = ((const float2*)YF)[((b * 40 + kx) * 20 + ky) * 64 + co];
        yfs[kx * 40 + 2 * ky] = v.x;
        yfs[kx * 40 + 2 * ky + 1] = v.y;
    }
    cts[tid] = ct[tid]; sts[tid] = st[tid];
    __syncthreads();
    int h = tid;
    float accr[20], acci[20];
#pragma unroll
    for (int q = 0; q < 20; ++q) { accr[q] = 0.f; acci[q] = 0.f; }
#pragma unroll 2
    for (int kxi = 0; kxi < 40; ++kxi) {
        int kxa = kxi < 20 ? kxi : kxi + 216;
        int r = (kxa * h) & 255;
        float cc = cts[r], sv = sts[r];
#pragma unroll
        for (int q = 0; q < 10; ++q) {
            float4 v = *(const float4*)&yfs[kxi * 40 + (q << 2)];
            accr[2 * q]     += v.x * cc - v.y * sv;  acci[2 * q]     += v.x * sv + v.y * cc;
            accr[2 * q + 1] += v.z * cc - v.w * sv;  acci[2 * q + 1] += v.z * sv + v.w * cc;
        }
    }
    const float s = 1.f / 16.f;
    int base = (bc * 256 + h) * 40;
#pragma unroll
    for (int q = 0; q < 10; ++q) {
        float4 o4;
        o4.x = accr[2 * q] * s;     o4.y = acci[2 * q] * s;
        o4.z = accr[2 * q + 1] * s; o4.w = acci[2 * q + 1] * s;
        *(float4*)&Z[base + (q << 2)] = o4;
    }
}

// ------------------- stage D fused with 1x1 conv + bias + BN-stats accumulation
// pre[b][o][h][w] = sum_k A[o][k]*B[k][w] + cb[o];  A: [cw | Z-row], B: [hin-row ; Tw]
// B read straight from global (register pipeline); A broadcast from LDS.
// IN-PLACE SAFE: block (b,h) reads only row (b,:,h,:) and writes only row (b,:,h,:).
#define SPECFMA(B4, J) \
        acc[0][4*(J)+0] += a.x * B4.x; acc[0][4*(J)+1] += a.x * B4.y; \
        acc[0][4*(J)+2] += a.x * B4.z; acc[0][4*(J)+3] += a.x * B4.w; \
        acc[1][4*(J)+0] += a.y * B4.x; acc[1][4*(J)+1] += a.y * B4.y; \
        acc[1][4*(J)+2] += a.y * B4.z; acc[1][4*(J)+3] += a.y * B4.w; \
        acc[2][4*(J)+0] += a.z * B4.x; acc[2][4*(J)+1] += a.z * B4.y; \
        acc[2][4*(J)+2] += a.z * B4.z; acc[2][4*(J)+3] += a.z * B4.w; \
        acc[3][4*(J)+0] += a.w * B4.x; acc[3][4*(J)+1] += a.w * B4.y; \
        acc[3][4*(J)+2] += a.w * B4.z; acc[3][4*(J)+3] += a.w * B4.w;

__global__ __launch_bounds__(256, 3) void speclin_k(const float* __restrict__ hin,
                                                    const float* __restrict__ Z,
                                                    const float* __restrict__ cwTl,
                                                    const float* __restrict__ TwT,
                                                    const float* __restrict__ cbl,
                                                    float* __restrict__ pre,
                                                    float* __restrict__ statsl) {
    __shared__ __align__(16) float As[104 * 64];
    int tid = threadIdx.x;
    int bh = blockIdx.x;
    int b = bh >> 8, h = bh & 255;
    int to = tid >> 4, tw = tid & 15;
    int o0 = to << 2, w0 = tw << 4;

    for (int i = tid; i < 4096; i += 256) As[i] = cwTl[i];
    for (int i = tid; i < 2560; i += 256) {       // o-fastest: conflict-free LDS writes
        int o = i & 63, kp = i >> 6;
        As[((64 + kp) << 6) + o] = Z[((b * 64 + o) * 256 + h) * 40 + kp];
    }
    __syncthreads();

    float acc[4][16];
#pragma unroll
    for (int i = 0; i < 4; ++i)
#pragma unroll
        for (int j = 0; j < 16; ++j) acc[i][j] = 0.f;

    const float* bp = hin + (((b << 6) * 256 + h) << 8) + w0;
    float4 c0 = *(const float4*)(bp);
    float4 c1 = *(const float4*)(bp + 4);
    float4 c2 = *(const float4*)(bp + 8);
    float4 c3 = *(const float4*)(bp + 12);

#pragma unroll 4
    for (int k = 0; k < 104; ++k) {
        const float* np;
        if (k < 63)       np = bp + 65536;
        else if (k < 103) np = TwT + ((k - 63) << 8) + w0;
        else              np = bp;
        float4 n0 = *(const float4*)(np);
        float4 n1 = *(const float4*)(np + 4);
        float4 n2 = *(const float4*)(np + 8);
        float4 n3 = *(const float4*)(np + 12);
        bp = np;
        float4 a = *(const float4*)&As[(k << 6) + o0];
        SPECFMA(c0, 0) SPECFMA(c1, 1) SPECFMA(c2, 2) SPECFMA(c3, 3)
        c0 = n0; c1 = n1; c2 = n2; c3 = n3;
    }

    float cbv[4];
#pragma unroll
    for (int i = 0; i < 4; ++i) cbv[i] = cbl[o0 + i];
#pragma unroll
    for (int i = 0; i < 4; ++i) {
        float sum = 0.f, sq = 0.f;
        int obase = ((((b << 6) + o0 + i) << 8) + h) << 8;
#pragma unroll
        for (int jg = 0; jg < 4; ++jg) {
            float4 v;
            v.x = acc[i][4 * jg + 0] + cbv[i];
            v.y = acc[i][4 * jg + 1] + cbv[i];
            v.z = acc[i][4 * jg + 2] + cbv[i];
            v.w = acc[i][4 * jg + 3] + cbv[i];
            *(float4*)&pre[obase + w0 + (jg << 2)] = v;
            sum += v.x + v.y + v.z + v.w;
            sq  += v.x * v.x + v.y * v.y + v.z * v.z + v.w * v.w;
        }
        sum += __shfl_xor(sum, 1); sq += __shfl_xor(sq, 1);
        sum += __shfl_xor(sum, 2); sq += __shfl_xor(sq, 2);
        sum += __shfl_xor(sum, 4); sq += __shfl_xor(sq, 4);
        sum += __shfl_xor(sum, 8); sq += __shfl_xor(sq, 8);
        if (tw == 0) {
            atomicAdd(&statsl[o0 + i], sum);
            atomicAdd(&statsl[64 + o0 + i], sq);
        }
    }
}

// ----------------- fc1+relu+fc2, with layer-3 BN folded into fc1 weights/bias
__global__ __launch_bounds__(512, 4) void fc12_k(const float* __restrict__ hin,
                                                 const float* __restrict__ statsl,
                                                 const float* __restrict__ g,
                                                 const float* __restrict__ bt,
                                                 const float* __restrict__ w1, const float* __restrict__ b1,
                                                 const float* __restrict__ w2, const float* __restrict__ b2,
                                                 float* __restrict__ out) {
    __shared__ __align__(16) float As[8192];   // sc_c * fc1_w[c][d]
    __shared__ float scs[64], shs[64], bias2[128];
    __shared__ float red[8192];
    int tid = threadIdx.x;
    int bh = blockIdx.x;
    int b = bh >> 8, h = bh & 255;
    int td = tid >> 4, tw = tid & 15;
    int d0 = td << 2, w0 = tw << 4;

    if (tid < 64) {
        float mean = statsl[tid] * (1.f / 524288.f);
        float var = statsl[64 + tid] * (1.f / 524288.f) - mean * mean;
        float s = g[tid] * rsqrtf(var + 1e-5f);
        scs[tid] = s; shs[tid] = bt[tid] - mean * s;
    }
    __syncthreads();
    for (int i = tid; i < 8192; i += 512) As[i] = w1[i] * scs[i >> 7];
    if (tid < 128) {
        float a = b1[tid];
        for (int c = 0; c < 64; ++c) a += shs[c] * w1[c * 128 + tid];
        bias2[tid] = a;
    }
    __syncthreads();

    float acc[4][16];
#pragma unroll
    for (int i = 0; i < 4; ++i)
#pragma unroll
        for (int j = 0; j < 16; ++j) acc[i][j] = 0.f;

    const float* bp = hin + (((b << 6) * 256 + h) << 8) + w0;
    float4 c0 = *(const float4*)(bp);
    float4 c1 = *(const float4*)(bp + 4);
    float4 c2 = *(const float4*)(bp + 8);
    float4 c3 = *(const float4*)(bp + 12);

#pragma unroll 4
    for (int k = 0; k < 64; ++k) {
        const float* np = (k < 63) ? bp + 65536 : bp;
        float4 n0 = *(const float4*)(np);
        float4 n1 = *(const float4*)(np + 4);
        float4 n2 = *(const float4*)(np + 8);
        float4 n3 = *(const float4*)(np + 12);
        bp = np;
        float4 a = *(const float4*)&As[(k << 7) + d0];
        SPECFMA(c0, 0) SPECFMA(c1, 1) SPECFMA(c2, 2) SPECFMA(c3, 3)
        c0 = n0; c1 = n1; c2 = n2; c3 = n3;
    }

    float bb[4], wv[4];
#pragma unroll
    for (int i = 0; i < 4; ++i) { bb[i] = bias2[d0 + i]; wv[i] = w2[d0 + i]; }
#pragma unroll
    for (int j = 0; j < 16; ++j) {
        float p = 0.f;
#pragma unroll
        for (int i = 0; i < 4; ++i) p += fmaxf(acc[i][j] + bb[i], 0.f) * wv[i];
        red[td * 256 + w0 + j] = p;
    }
    __syncthreads();
    if (tid < 256) {
        float s2 = b2[0];
#pragma unroll 8
        for (int t2 = 0; t2 < 32; ++t2) s2 += red[t2 * 256 + tid];
        out[(b * 256 + h) * 256 + tid] = s2;
    }
}

// ------------------------------------------------------------------- launcher
extern "C" void kernel_launch(void* const* d_in, const int* in_sizes, int n_in,
                              void* d_out, int out_size, void* d_ws, size_t ws_size,
                              hipStream_t stream) {
    (void)in_sizes; (void)n_in; (void)out_size; (void)ws_size;
    const float* x     = (const float*)d_in[0];
    const float* fc0_w = (const float*)d_in[1];
    const float* fc0_b = (const float*)d_in[2];
    const float* sw1   = (const float*)d_in[3];
    const float* sw2   = (const float*)d_in[4];
    const float* cw    = (const float*)d_in[5];
    const float* cb    = (const float*)d_in[6];
    const float* bng   = (const float*)d_in[7];
    const float* bnb   = (const float*)d_in[8];
    const float* fc1_w = (const float*)d_in[9];
    const float* fc1_b = (const float*)d_in[10];
    const float* fc2_w = (const float*)d_in[11];
    const float* fc2_b = (const float*)d_in[12];
    float* out = (float*)d_out;

    float* ws = (float*)d_ws;
    float* hbuf   = ws;                       // 33,554,432  (in-place activations)
    float* tz     = hbuf + 33554432;          // 5,242,880   (stage-A T / stage-C Z share)
    float* xf     = tz + 5242880;             // 819,200
    float* yf     = xf + 819200;              // 819,200
    float* costab = yf + 819200;              // 256
    float* sintab = costab + 256;             // 256
    float* EA     = sintab + 256;             // 10,240
    float* Tw     = EA + 10240;               // 10,240
    float* cwT    = Tw + 10240;               // 16,384
    float* stats  = cwT + 16384;              // 512   (4 layers x [sum64|sumsq64])

    init_k<<<147, 256, 0, stream>>>(cw, costab, sintab, EA, Tw, cwT, stats);
    fc0_k<<<2048, 256, 0, stream>>>(x, fc0_w, fc0_b, hbuf);

    for (int l = 0; l < 4; ++l) {
        if (l == 0)
            dftw_k<<<2048, 128, 0, stream>>>(hbuf, EA, tz, stats, bng, bnb, 0);
        else
            dftw_k<<<2048, 128, 0, stream>>>(hbuf, EA, tz, stats + (l - 1) * 128,
                                             bng + (l - 1) * 64, bnb + (l - 1) * 64, 1);
        dfth_k<<<512, 256, 0, stream>>>(tz, costab, sintab, xf);
        eins_k<<<800, 512, 0, stream>>>(xf, sw1 + l * 3276800, sw2 + l * 3276800, yf);
        idfth_k<<<512, 256, 0, stream>>>(yf, costab, sintab, tz);
        speclin_k<<<2048, 256, 0, stream>>>(hbuf, tz, cwT + l * 4096, Tw, cb + l * 64,
                                            hbuf, stats + l * 128);
    }
    fc12_k<<<2048, 512, 0, stream>>>(hbuf, stats + 3 * 128, bng + 3 * 64, bnb + 3 * 64,
                                     fc1_w, fc1_b, fc2_w, fc2_b, out);
}

// Round 4
// 1747.819 us; speedup vs baseline: 1.3955x; 1.3955x over previous
//
#include <hip/hip_runtime.h>
#include <hip/hip_bf16.h>

// FNO2D: B=8, C=64, H=W=256, MODES=20.
// Spectral conv as partial DFTs (only 40x20 modes used). In-place activations.
// BN+ReLU fused into next-layer dftw (l=1..3) and into fc12 (layer 3).
// speclin/fc12: LDS-staged B with conflict-free vectorized reads (4o x 16 interleaved w).
// eins: one-time bf16 weight transpose to [xy][i][o] (coalesced), gated on ws_size.

// ---------------------------------------------------------------- init tables
__global__ __launch_bounds__(256) void init_k(const float* __restrict__ cw,
                                              float* __restrict__ costab, float* __restrict__ sintab,
                                              float* __restrict__ EA, float* __restrict__ Tw,
                                              float* __restrict__ cwT, float* __restrict__ stats) {
    int idx = blockIdx.x * 256 + threadIdx.x;
    const float PH = 6.28318530717958647692f / 256.f;
    if (idx < 256) {
        float s, c; sincosf(idx * PH, &s, &c);
        costab[idx] = c; sintab[idx] = s;
    } else if (idx < 256 + 10240) {            // EA[w][2*ky+p]: forward DFT along W
        int e = idx - 256;
        int w = e / 40, n = e % 40, ky = n >> 1;
        int r = (ky * w) & 255;
        float s, c; sincosf(r * PH, &s, &c);
        EA[e] = (n & 1) ? -s : c;
    } else if (idx < 256 + 20480) {            // Tw[kp][w]: irfft along W (ortho, Im(z0) dropped)
        int e = idx - 10496;
        int kp = e >> 8, w = e & 255;
        int ky = kp >> 1, p = kp & 1;
        int r = (ky * w) & 255;
        float s, c; sincosf(r * PH, &s, &c);
        float v;
        if (ky == 0) v = p ? 0.f : (1.f / 16.f);
        else         v = p ? (-2.f / 16.f) * s : (2.f / 16.f) * c;
        Tw[e] = v;
    } else if (idx < 256 + 20480 + 16384) {    // cwT[l][i][o] = cw[l][o][i]
        int e = idx - 20736;
        int l = e >> 12, r2 = e & 4095;
        int i = r2 >> 6, o = r2 & 63;
        cwT[e] = cw[(l << 12) + (o << 6) + i];
    } else if (idx < 256 + 20480 + 16384 + 512) {
        stats[idx - 37120] = 0.f;              // zero BN-stats accumulators
    }
}

// ---------------------- one-time weight transpose: W[l][i][o][x][y] -> bf16 [t2][xy][i][o]
// t2 = l*2 + tbl. Reads: per-lane 128 B contiguous (sector-efficient).
// Writes: 64 lanes x 4 B consecutive o -> 256 B coalesced.
__global__ __launch_bounds__(256) void wtrans_k(const float* __restrict__ sw1,
                                                const float* __restrict__ sw2,
                                                unsigned int* __restrict__ wt) {
    int gid = blockIdx.x * 4 + (threadIdx.x >> 6);   // 0..12799
    int o = threadIdx.x & 63;
    int xyc = gid % 25;
    int i = (gid / 25) & 63;
    int t2 = gid / 1600;                             // 0..7
    const float* src = ((t2 & 1) ? sw2 : sw1) + (t2 >> 1) * 3276800;
    const float* sp = src + ((i * 64 + o) * 400 + xyc * 16) * 2;
    unsigned int* dp = wt + (size_t)(t2 * 400 + xyc * 16) * 4096 + i * 64 + o;
#pragma unroll
    for (int j = 0; j < 16; ++j) {
        float re = sp[2 * j], im = sp[2 * j + 1];
        unsigned int ur = __float_as_uint(re), ui = __float_as_uint(im);
        ur = (ur + 0x7fffu + ((ur >> 16) & 1u)) >> 16;        // RNE to bf16
        ui = (ui + 0x7fffu + ((ui >> 16) & 1u)) & 0xffff0000u;
        dp[(size_t)j * 4096] = ur | ui;
    }
}

// ------------------------------------------------------------------------ fc0
__global__ __launch_bounds__(256) void fc0_k(const float* __restrict__ x,
                                             const float* __restrict__ w,
                                             const float* __restrict__ bias,
                                             float* __restrict__ outb) {
    __shared__ float ws[768];
    __shared__ float bs[64];
    int tid = threadIdx.x;
    for (int i = tid; i < 768; i += 256) ws[i] = w[i];
    if (tid < 64) bs[tid] = bias[tid];
    __syncthreads();
    int pix = blockIdx.x * 256 + tid;           // 0..524287
    int b = pix >> 16, hw = pix & 65535;
    float xv[12];
#pragma unroll
    for (int t = 0; t < 12; ++t) xv[t] = x[pix * 12 + t];
    int base = (b << 22) + hw;
    for (int c = 0; c < 64; ++c) {
        float a = bs[c];
#pragma unroll
        for (int t = 0; t < 12; ++t) a += xv[t] * ws[t * 64 + c];
        outb[base + (c << 16)] = a;
    }
}

// ------------------- stage A: DFT along W (GEMM), optionally fused BN+ReLU
__global__ __launch_bounds__(128) void dftw_k(float* __restrict__ X,
                                              const float* __restrict__ EA,
                                              float* __restrict__ T,
                                              const float* __restrict__ statsl,
                                              const float* __restrict__ g,
                                              const float* __restrict__ bt,
                                              int fuse) {
    __shared__ __align__(16) float Xs[32 * 68];   // transposed [k][m]
    __shared__ float Es[32 * 40];
    int tid = threadIdx.x;
    int tm = tid >> 3, tn = tid & 7;
    int row0 = blockIdx.x << 6;
    float sc = 1.f, sh = 0.f;
    if (fuse) {
        int c = (row0 >> 8) & 63;
        float mean = statsl[c] * (1.f / 524288.f);
        float var = statsl[64 + c] * (1.f / 524288.f) - mean * mean;
        sc = g[c] * rsqrtf(var + 1e-5f);
        sh = bt[c] - mean * sc;
    }
    float acc[4][5];
#pragma unroll
    for (int i = 0; i < 4; ++i)
#pragma unroll
        for (int j = 0; j < 5; ++j) acc[i][j] = 0.f;

    for (int kc = 0; kc < 256; kc += 32) {
        __syncthreads();
#pragma unroll
        for (int r = 0; r < 4; ++r) {
            int m = tm + (r << 4);
            float4 v = *(const float4*)&X[(row0 + m) * 256 + kc + (tn << 2)];
            if (fuse) {
                v.x = fmaxf(fmaf(v.x, sc, sh), 0.f);
                v.y = fmaxf(fmaf(v.y, sc, sh), 0.f);
                v.z = fmaxf(fmaf(v.z, sc, sh), 0.f);
                v.w = fmaxf(fmaf(v.w, sc, sh), 0.f);
                *(float4*)&X[(row0 + m) * 256 + kc + (tn << 2)] = v;
            }
            int kb = tn << 2;
            Xs[(kb + 0) * 68 + m] = v.x;
            Xs[(kb + 1) * 68 + m] = v.y;
            Xs[(kb + 2) * 68 + m] = v.z;
            Xs[(kb + 3) * 68 + m] = v.w;
        }
        for (int i = tid; i < 1280; i += 128) Es[i] = EA[kc * 40 + i];
        __syncthreads();
#pragma unroll 8
        for (int kk = 0; kk < 32; ++kk) {
            float4 a = *(const float4*)&Xs[kk * 68 + (tm << 2)];
#pragma unroll
            for (int j = 0; j < 5; ++j) {
                float bv = Es[kk * 40 + tn * 5 + j];
                acc[0][j] += a.x * bv;
                acc[1][j] += a.y * bv;
                acc[2][j] += a.z * bv;
                acc[3][j] += a.w * bv;
            }
        }
    }
#pragma unroll
    for (int i = 0; i < 4; ++i) {
        int row = row0 + (tm << 2) + i;
#pragma unroll
        for (int j = 0; j < 5; ++j) T[row * 40 + tn * 5 + j] = acc[i][j];
    }
}

// ------------------------------------------- stage B: DFT along H (256 -> 40 rows)
__global__ __launch_bounds__(256) void dfth_k(const float* __restrict__ T,
                                              const float* __restrict__ ct, const float* __restrict__ st,
                                              float* __restrict__ XF) {
    __shared__ __align__(16) float Ts[10240];
    __shared__ float cts[256], sts[256];
    int tid = threadIdx.x;
    int bc = blockIdx.x;
    for (int i = tid; i < 10240; i += 256) Ts[i] = T[bc * 10240 + i];
    cts[tid] = ct[tid]; sts[tid] = st[tid];
    __syncthreads();
    if (tid < 200) {
        int kxi = tid / 5, kyg = tid % 5;
        int kxa = kxi < 20 ? kxi : kxi + 216;
        float ar0 = 0, ai0 = 0, ar1 = 0, ai1 = 0, ar2 = 0, ai2 = 0, ar3 = 0, ai3 = 0;
        int r = 0;
        for (int h = 0; h < 256; ++h) {
            float cc = cts[r], sv = sts[r];
            r = (r + kxa) & 255;
            float4 v0 = *(const float4*)&Ts[h * 40 + (kyg << 3)];
            float4 v1 = *(const float4*)&Ts[h * 40 + (kyg << 3) + 4];
            ar0 += v0.x * cc + v0.y * sv;  ai0 += v0.y * cc - v0.x * sv;
            ar1 += v0.z * cc + v0.w * sv;  ai1 += v0.w * cc - v0.z * sv;
            ar2 += v1.x * cc + v1.y * sv;  ai2 += v1.y * cc - v1.x * sv;
            ar3 += v1.z * cc + v1.w * sv;  ai3 += v1.w * cc - v1.z * sv;
        }
        int b = bc >> 6, c = bc & 63;
        const float s = 1.f / 256.f;
        int A = (b * 40 + kxi) * 20 + (kyg << 2);
        float2* O = (float2*)XF;
        O[(A + 0) * 64 + c] = make_float2(ar0 * s, ai0 * s);
        O[(A + 1) * 64 + c] = make_float2(ar1 * s, ai1 * s);
        O[(A + 2) * 64 + c] = make_float2(ar2 * s, ai2 * s);
        O[(A + 3) * 64 + c] = make_float2(ar3 * s, ai3 * s);
    }
}

// ---------------------------------------------------------------- mode einsum
// transposed-weight path: wt[t2][xy][i][o] bf16x2, coalesced reads
__global__ __launch_bounds__(512) void eins_t_k(const float* __restrict__ XF,
                                                const unsigned int* __restrict__ wtl,
                                                float* __restrict__ YF) {
    __shared__ float xfs[1024];
    int tid = threadIdx.x;
    int x = blockIdx.x / 20, y = blockIdx.x % 20;
    for (int i = tid; i < 1024; i += 512) {
        int b = i >> 7, rr = i & 127;
        xfs[i] = XF[(b * 40 + x) * 2560 + y * 128 + rr];
    }
    __syncthreads();
    int b = tid >> 6, o = tid & 63;
    const unsigned int* wp = wtl + (size_t)(((x < 20 ? 0 : 400) + (x % 20) * 20 + y)) * 4096 + o;
    float ar = 0.f, ai = 0.f;
#pragma unroll 8
    for (int i = 0; i < 64; ++i) {
        unsigned int wv = wp[i << 6];
        float wr = __uint_as_float(wv << 16);
        float wi = __uint_as_float(wv & 0xffff0000u);
        float xr = xfs[(b << 7) + (i << 1)];
        float xi = xfs[(b << 7) + (i << 1) + 1];
        ar += xr * wr - xi * wi;
        ai += xr * wi + xi * wr;
    }
    ((float2*)YF)[((b * 40 + x) * 20 + y) * 64 + o] = make_float2(ar, ai);
}

// fallback path (ws too small): read strided f32 weights directly
__global__ __launch_bounds__(512) void eins_k(const float* __restrict__ XF,
                                              const float* __restrict__ w1, const float* __restrict__ w2,
                                              float* __restrict__ YF) {
    __shared__ float xfs[1024];
    int tid = threadIdx.x;
    int x = blockIdx.x / 20, y = blockIdx.x % 20;
    for (int i = tid; i < 1024; i += 512) {
        int b = i >> 7, rr = i & 127;
        xfs[i] = XF[(b * 40 + x) * 2560 + y * 128 + rr];
    }
    __syncthreads();
    int b = tid >> 6, o = tid & 63;
    const float* wp = (x < 20) ? (w1 + (x * 20 + y) * 2) : (w2 + ((x - 20) * 20 + y) * 2);
    float ar = 0.f, ai = 0.f;
#pragma unroll 8
    for (int i = 0; i < 64; ++i) {
        float2 wv = *(const float2*)&wp[(i * 64 + o) * 800];
        float xr = xfs[(b << 7) + (i << 1)];
        float xi = xfs[(b << 7) + (i << 1) + 1];
        ar += xr * wv.x - xi * wv.y;
        ai += xr * wv.y + xi * wv.x;
    }
    ((float2*)YF)[((b * 40 + x) * 20 + y) * 64 + o] = make_float2(ar, ai);
}

// ------------------------------------ stage C: inverse (full complex) DFT along H
__global__ __launch_bounds__(256) void idfth_k(const float* __restrict__ YF,
                                               const float* __restrict__ ct, const float* __restrict__ st,
                                               float* __restrict__ Z) {
    __shared__ __align__(16) float yfs[1600];
    __shared__ float cts[256], sts[256];
    int tid = threadIdx.x;
    int bc = blockIdx.x;
    int b = bc >> 6, co = bc & 63;
    for (int i = tid; i < 800; i += 256) {
        int kx = i / 20, ky = i % 20;
        float2 v = ((const float2*)YF)[((b * 40 + kx) * 20 + ky) * 64 + co];
        yfs[kx * 40 + 2 * ky] = v.x;
        yfs[kx * 40 + 2 * ky + 1] = v.y;
    }
    cts[tid] = ct[tid]; sts[tid] = st[tid];
    __syncthreads();
    int h = tid;
    float accr[20], acci[20];
#pragma unroll
    for (int q = 0; q < 20; ++q) { accr[q] = 0.f; acci[q] = 0.f; }
#pragma unroll 2
    for (int kxi = 0; kxi < 40; ++kxi) {
        int kxa = kxi < 20 ? kxi : kxi + 216;
        int r = (kxa * h) & 255;
        float cc = cts[r], sv = sts[r];
#pragma unroll
        for (int q = 0; q < 10; ++q) {
            float4 v = *(const float4*)&yfs[kxi * 40 + (q << 2)];
            accr[2 * q]     += v.x * cc - v.y * sv;  acci[2 * q]     += v.x * sv + v.y * cc;
            accr[2 * q + 1] += v.z * cc - v.w * sv;  acci[2 * q + 1] += v.z * sv + v.w * cc;
        }
    }
    const float s = 1.f / 16.f;
    int base = (bc * 256 + h) * 40;
#pragma unroll
    for (int q = 0; q < 10; ++q) {
        float4 o4;
        o4.x = accr[2 * q] * s;     o4.y = acci[2 * q] * s;
        o4.z = accr[2 * q + 1] * s; o4.w = acci[2 * q + 1] * s;
        *(float4*)&Z[base + (q << 2)] = o4;
    }
}

// ------------------- stage D fused with 1x1 conv + bias + BN-stats accumulation
// C[64o x 256w] = A[64o x 104k] * B[104k x 256w] + cb; A = [cwT | Z-row], B = [hin-row ; Tw]
// Thread (to,tw): 4 o x 16 interleaved w (w = j*64 + tw*4 + e). All LDS reads 2-way max.
#define SFMA4(A4, B4, J) \
    acc[0][J].x += A4.x * B4.x; acc[0][J].y += A4.x * B4.y; acc[0][J].z += A4.x * B4.z; acc[0][J].w += A4.x * B4.w; \
    acc[1][J].x += A4.y * B4.x; acc[1][J].y += A4.y * B4.y; acc[1][J].z += A4.y * B4.z; acc[1][J].w += A4.y * B4.w; \
    acc[2][J].x += A4.z * B4.x; acc[2][J].y += A4.z * B4.y; acc[2][J].z += A4.z * B4.z; acc[2][J].w += A4.z * B4.w; \
    acc[3][J].x += A4.w * B4.x; acc[3][J].y += A4.w * B4.y; acc[3][J].z += A4.w * B4.z; acc[3][J].w += A4.w * B4.w;

__global__ __launch_bounds__(256, 4) void speclin_k(const float* __restrict__ hin,
                                                    const float* __restrict__ Z,
                                                    const float* __restrict__ cwTl,
                                                    const float* __restrict__ TwT,
                                                    const float* __restrict__ cbl,
                                                    float* __restrict__ pre,
                                                    float* __restrict__ statsl) {
    __shared__ __align__(16) float As[104 * 64];   // [k][o]
    __shared__ __align__(16) float Bs[13 * 256];   // [kk][w]
    int tid = threadIdx.x;
    int bh = blockIdx.x;
    int b = bh >> 8, h = bh & 255;
    int to = tid >> 4, tw = tid & 15;
    int o0 = to << 2;

    for (int i = tid; i < 4096; i += 256) As[i] = cwTl[i];
    for (int i4 = tid; i4 < 640; i4 += 256) {      // Z: [40kp][64o] section of A
        int o = i4 / 10, q = i4 - o * 10;
        float4 v = *(const float4*)&Z[((b * 64 + o) * 256 + h) * 40 + (q << 2)];
        As[(64 + (q << 2) + 0) * 64 + o] = v.x;
        As[(64 + (q << 2) + 1) * 64 + o] = v.y;
        As[(64 + (q << 2) + 2) * 64 + o] = v.z;
        As[(64 + (q << 2) + 3) * 64 + o] = v.w;
    }

    float4 acc[4][4];
#pragma unroll
    for (int i = 0; i < 4; ++i)
#pragma unroll
        for (int j = 0; j < 4; ++j) acc[i][j] = make_float4(0.f, 0.f, 0.f, 0.f);

    const float* hrow = hin + (((b << 6) * 256 + h) << 8);
    for (int ch = 0; ch < 8; ++ch) {
        __syncthreads();
        for (int i4 = tid; i4 < 832; i4 += 256) {
            int kk = i4 >> 6, w4 = i4 & 63;
            int gk = ch * 13 + kk;
            const float* sp = (gk < 64) ? (hrow + (gk << 16)) : (TwT + ((gk - 64) << 8));
            *(float4*)&Bs[(kk << 8) + (w4 << 2)] = *(const float4*)&sp[w4 << 2];
        }
        __syncthreads();
#pragma unroll
        for (int kk = 0; kk < 13; ++kk) {
            float4 a = *(const float4*)&As[((ch * 13 + kk) << 6) + o0];
#pragma unroll
            for (int j = 0; j < 4; ++j) {
                float4 bv = *(const float4*)&Bs[(kk << 8) + (j << 6) + (tw << 2)];
                SFMA4(a, bv, j)
            }
        }
    }

    float cbv[4];
#pragma unroll
    for (int i = 0; i < 4; ++i) cbv[i] = cbl[o0 + i];
#pragma unroll
    for (int i = 0; i < 4; ++i) {
        float sum = 0.f, sq = 0.f;
        int obase = ((((b << 6) + o0 + i) << 8) + h) << 8;
#pragma unroll
        for (int j = 0; j < 4; ++j) {
            float4 v = acc[i][j];
            v.x += cbv[i]; v.y += cbv[i]; v.z += cbv[i]; v.w += cbv[i];
            *(float4*)&pre[obase + (j << 6) + (tw << 2)] = v;
            sum += v.x + v.y + v.z + v.w;
            sq  += v.x * v.x + v.y * v.y + v.z * v.z + v.w * v.w;
        }
        sum += __shfl_xor(sum, 1); sq += __shfl_xor(sq, 1);
        sum += __shfl_xor(sum, 2); sq += __shfl_xor(sq, 2);
        sum += __shfl_xor(sum, 4); sq += __shfl_xor(sq, 4);
        sum += __shfl_xor(sum, 8); sq += __shfl_xor(sq, 8);
        if (tw == 0) {
            atomicAdd(&statsl[o0 + i], sum);
            atomicAdd(&statsl[64 + o0 + i], sq);
        }
    }
}

// ----------------- fc1+relu+fc2, layer-3 BN folded into fc1 weights/bias
__global__ __launch_bounds__(512, 2) void fc12_k(const float* __restrict__ hin,
                                                 const float* __restrict__ statsl,
                                                 const float* __restrict__ g,
                                                 const float* __restrict__ bt,
                                                 const float* __restrict__ w1, const float* __restrict__ b1,
                                                 const float* __restrict__ w2, const float* __restrict__ b2,
                                                 float* __restrict__ out) {
    __shared__ __align__(16) float As[8192];   // sc_c * fc1_w[c][d]
    __shared__ __align__(16) float Bs[4096];   // k-chunk 16 x 256
    __shared__ float scs[64], shs[64], bias2[128];
    __shared__ float red[2048];                // [8 waves][256 w]
    int tid = threadIdx.x;
    int bh = blockIdx.x;
    int b = bh >> 8, h = bh & 255;
    int td = tid >> 4, tw = tid & 15;
    int d0 = td << 2;

    if (tid < 64) {
        float mean = statsl[tid] * (1.f / 524288.f);
        float var = statsl[64 + tid] * (1.f / 524288.f) - mean * mean;
        float s = g[tid] * rsqrtf(var + 1e-5f);
        scs[tid] = s; shs[tid] = bt[tid] - mean * s;
    }
    __syncthreads();
    for (int i = tid; i < 8192; i += 512) As[i] = w1[i] * scs[i >> 7];
    if (tid < 128) {
        float a = b1[tid];
        for (int c = 0; c < 64; ++c) a += shs[c] * w1[c * 128 + tid];
        bias2[tid] = a;
    }

    float4 acc[4][4];
#pragma unroll
    for (int i = 0; i < 4; ++i)
#pragma unroll
        for (int j = 0; j < 4; ++j) acc[i][j] = make_float4(0.f, 0.f, 0.f, 0.f);

    const float* hrow = hin + (((b << 6) * 256 + h) << 8);
    for (int ch = 0; ch < 4; ++ch) {
        __syncthreads();
        for (int i4 = tid; i4 < 1024; i4 += 512) {
            int kk = i4 >> 6, w4 = i4 & 63;
            *(float4*)&Bs[(kk << 8) + (w4 << 2)] =
                *(const float4*)&hrow[((ch * 16 + kk) << 16) + (w4 << 2)];
        }
        __syncthreads();
#pragma unroll
        for (int kk = 0; kk < 16; ++kk) {
            float4 a = *(const float4*)&As[((ch * 16 + kk) << 7) + d0];
#pragma unroll
            for (int j = 0; j < 4; ++j) {
                float4 bv = *(const float4*)&Bs[(kk << 8) + (j << 6) + (tw << 2)];
                SFMA4(a, bv, j)
            }
        }
    }

    float bb[4], wv[4];
#pragma unroll
    for (int i = 0; i < 4; ++i) { bb[i] = bias2[d0 + i]; wv[i] = w2[d0 + i]; }
    float p[16];
#pragma unroll
    for (int j = 0; j < 4; ++j) {
#pragma unroll
        for (int e = 0; e < 4; ++e) {
            float* a0 = (float*)&acc[0][j];
            float v = fmaxf(((float*)&acc[0][j])[e] + bb[0], 0.f) * wv[0]
                    + fmaxf(((float*)&acc[1][j])[e] + bb[1], 0.f) * wv[1]
                    + fmaxf(((float*)&acc[2][j])[e] + bb[2], 0.f) * wv[2]
                    + fmaxf(((float*)&acc[3][j])[e] + bb[3], 0.f) * wv[3];
            (void)a0;
            p[4 * j + e] = v;
        }
    }
#pragma unroll
    for (int q = 0; q < 16; ++q) {
        p[q] += __shfl_xor(p[q], 16);
        p[q] += __shfl_xor(p[q], 32);
    }
    int wave = tid >> 6;
    if (((tid >> 4) & 3) == 0) {
#pragma unroll
        for (int j = 0; j < 4; ++j) {
            float4 v = make_float4(p[4 * j], p[4 * j + 1], p[4 * j + 2], p[4 * j + 3]);
            *(float4*)&red[(wave << 8) + (j << 6) + (tw << 2)] = v;
        }
    }
    __syncthreads();
    if (tid < 256) {
        float s2 = b2[0];
#pragma unroll
        for (int t2 = 0; t2 < 8; ++t2) s2 += red[(t2 << 8) + tid];
        out[(b * 256 + h) * 256 + tid] = s2;
    }
}

// ------------------------------------------------------------------- launcher
extern "C" void kernel_launch(void* const* d_in, const int* in_sizes, int n_in,
                              void* d_out, int out_size, void* d_ws, size_t ws_size,
                              hipStream_t stream) {
    (void)in_sizes; (void)n_in; (void)out_size;
    const float* x     = (const float*)d_in[0];
    const float* fc0_w = (const float*)d_in[1];
    const float* fc0_b = (const float*)d_in[2];
    const float* sw1   = (const float*)d_in[3];
    const float* sw2   = (const float*)d_in[4];
    const float* cw    = (const float*)d_in[5];
    const float* cb    = (const float*)d_in[6];
    const float* bng   = (const float*)d_in[7];
    const float* bnb   = (const float*)d_in[8];
    const float* fc1_w = (const float*)d_in[9];
    const float* fc1_b = (const float*)d_in[10];
    const float* fc2_w = (const float*)d_in[11];
    const float* fc2_b = (const float*)d_in[12];
    float* out = (float*)d_out;

    float* ws = (float*)d_ws;
    float* hbuf   = ws;                       // 33,554,432  (in-place activations)
    float* tz     = hbuf + 33554432;          // 5,242,880
    float* xf     = tz + 5242880;             // 819,200
    float* yf     = xf + 819200;              // 819,200
    float* costab = yf + 819200;              // 256
    float* sintab = costab + 256;             // 256
    float* EA     = sintab + 256;             // 10,240
    float* Tw     = EA + 10240;               // 10,240
    float* cwT    = Tw + 10240;               // 16,384
    float* stats  = cwT + 16384;              // 512
    unsigned int* wt = (unsigned int*)(stats + 512);   // 13,107,200 u32 (optional)

    size_t base_floats = 40473600 + 512;      // through stats
    int use_wt = (ws_size >= (base_floats + 13107200ull) * 4ull) ? 1 : 0;

    init_k<<<147, 256, 0, stream>>>(cw, costab, sintab, EA, Tw, cwT, stats);
    if (use_wt) wtrans_k<<<3200, 256, 0, stream>>>(sw1, sw2, wt);
    fc0_k<<<2048, 256, 0, stream>>>(x, fc0_w, fc0_b, hbuf);

    for (int l = 0; l < 4; ++l) {
        if (l == 0)
            dftw_k<<<2048, 128, 0, stream>>>(hbuf, EA, tz, stats, bng, bnb, 0);
        else
            dftw_k<<<2048, 128, 0, stream>>>(hbuf, EA, tz, stats + (l - 1) * 128,
                                             bng + (l - 1) * 64, bnb + (l - 1) * 64, 1);
        dfth_k<<<512, 256, 0, stream>>>(tz, costab, sintab, xf);
        if (use_wt)
            eins_t_k<<<800, 512, 0, stream>>>(xf, wt + (size_t)l * 2 * 400 * 4096, yf);
        else
            eins_k<<<800, 512, 0, stream>>>(xf, sw1 + l * 3276800, sw2 + l * 3276800, yf);
        idfth_k<<<512, 256, 0, stream>>>(yf, costab, sintab, tz);
        speclin_k<<<2048, 256, 0, stream>>>(hbuf, tz, cwT + l * 4096, Tw, cb + l * 64,
                                            hbuf, stats + l * 128);
    }
    fc12_k<<<2048, 512, 0, stream>>>(hbuf, stats + 3 * 128, bng + 3 * 64, bnb + 3 * 64,
                                     fc1_w, fc1_b, fc2_w, fc2_b, out);
}